// Round 1
// baseline (7813.697 us; speedup 1.0000x reference)
//
#include <hip/hip_runtime.h>
#include <cmath>

#define NB   32
#define TE   128
#define TD   32
#define VOC  32000
#define EMB  256
#define HH   512
#define CTXD 1024

// ws layout (float offsets)
#define OX   64
#define OXR  (OX  + TE*NB*EMB)          // x reversed
#define OHS  (OXR + TE*NB*EMB)          // hstep [TE+1][2][NB][HH]
#define OEO  (OHS + (TE+1)*2*NB*HH)     // enc_out [NB][TE][CTXD]
#define OEP  (OEO + NB*TE*CTXD)         // epre [NB][TE][8]
#define OHD  (OEP + NB*TE*8)            // hdec [TD+1][NB][HH]
#define OCX  (OHD + (TD+1)*NB*HH)       // ctx  [TD][NB][CTXD]
#define WSEND (OCX + TD*NB*CTXD)        // 12,140,608 floats ~48.6MB

__device__ __forceinline__ float sigf(float x) { return 1.0f / (1.0f + expf(-x)); }

__device__ __forceinline__ void stg1(float* p, float v) {
  __hip_atomic_store(p, v, __ATOMIC_RELAXED, __HIP_MEMORY_SCOPE_AGENT);
}

__device__ __forceinline__ void gbar(int* cnt, int* gen) {
  __syncthreads();  // compiler drains vmcnt before s_barrier
  if (threadIdx.x == 0) {
    int g = __hip_atomic_load(gen, __ATOMIC_RELAXED, __HIP_MEMORY_SCOPE_AGENT);
    int v = __hip_atomic_fetch_add(cnt, 1, __ATOMIC_RELEASE, __HIP_MEMORY_SCOPE_AGENT);
    if (v == (int)gridDim.x - 1) {
      __hip_atomic_store(cnt, 0, __ATOMIC_RELAXED, __HIP_MEMORY_SCOPE_AGENT);
      __hip_atomic_fetch_add(gen, 1, __ATOMIC_RELEASE, __HIP_MEMORY_SCOPE_AGENT);
    } else {
      int it = 0;
      while (__hip_atomic_load(gen, __ATOMIC_RELAXED, __HIP_MEMORY_SCOPE_AGENT) == g) {
        __builtin_amdgcn_s_sleep(2);
        if (++it > (1 << 21)) break;  // safety bail: garbage beats hang
      }
    }
  }
  __syncthreads();
}

// ---------------- BiLSTM scan: 256 blocks x 512 thr, persistent ----------------
// block: dir = bid>>7, ob = bid&127 -> rows {gate*512 + ob*4 + jj}, 16 rows x 32 b
__global__ void __launch_bounds__(512)
scan_kernel(const int* __restrict__ enc_in, const int* __restrict__ lens,
            const float* __restrict__ emb_src,
            const float* __restrict__ Wih_f, const float* __restrict__ Whh_f,
            const float* __restrict__ bih_f, const float* __restrict__ bhh_f,
            const float* __restrict__ Wih_b, const float* __restrict__ Whh_b,
            const float* __restrict__ bih_b, const float* __restrict__ bhh_b,
            float* __restrict__ ws)
{
  int* cnt = (int*)ws;
  int* gen = ((int*)ws) + 1;
  float* xf = ws + OX;
  float* xr = ws + OXR;
  float* hs = ws + OHS;
  float* eo = ws + OEO;

  const int tid = threadIdx.x;
  const int bid = blockIdx.x;

  asm volatile("buffer_inv sc1" ::: "memory");  // purge stale clean lines (poison)

  // pre-phase: embed x / x_rev (sc1: read cross-block after barrier), hstep[0]=0
  {
    const int gt = bid * 512 + tid;
    for (int i4 = gt; i4 < TE * NB * (EMB / 4); i4 += 131072) {
      int k4 = i4 & 63;
      int b  = (i4 >> 6) & 31;
      int t  = i4 >> 11;
      int tok = enc_in[b * TE + t];
      float4 v = *(const float4*)&emb_src[(size_t)tok * EMB + k4 * 4];
      float* d0 = &xf[((t * NB + b) * EMB) + k4 * 4];
      stg1(d0 + 0, v.x); stg1(d0 + 1, v.y); stg1(d0 + 2, v.z); stg1(d0 + 3, v.w);
      int L = lens[b];
      int tr = (t < L) ? (L - 1 - t) : t;
      int tok2 = enc_in[b * TE + tr];
      float4 v2 = *(const float4*)&emb_src[(size_t)tok2 * EMB + k4 * 4];
      float* d1 = &xr[((t * NB + b) * EMB) + k4 * 4];
      stg1(d1 + 0, v2.x); stg1(d1 + 1, v2.y); stg1(d1 + 2, v2.z); stg1(d1 + 3, v2.w);
    }
    for (int i = gt; i < 2 * NB * HH; i += 131072) stg1(&hs[i], 0.0f);
  }
  gbar(cnt, gen);

  const int dir = bid >> 7;
  const int ob  = bid & 127;
  const int j0  = ob * 4;
  const int ol  = tid >> 5, b = tid & 31;
  const int jj  = ol & 3, gate = ol >> 2;
  const int o   = gate * HH + j0 + jj;

  const float* Wih = dir ? Wih_b : Wih_f;
  const float* Whh = dir ? Whh_b : Whh_f;
  const float bias2 = dir ? (bih_b[o] + bhh_b[o]) : (bih_f[o] + bhh_f[o]);
  const float* xs = dir ? xr : xf;

  __shared__ __align__(16) float us[32 * 132];
  __shared__ float glds[16][32];

  const int ub = tid & 31;
  const int uj = tid >> 5;        // valid for tid<128 (updaters)
  const int Lu = lens[ub];
  float c_reg = 0.0f;

  for (int s = 0; s < TE; ++s) {
    float acc = 0.0f;
    for (int kc = 0; kc < 6; ++kc) {
      __syncthreads();
      {
        const float* src = (kc < 2) ? (xs + (size_t)(s * NB) * EMB + kc * 128)
                                    : (hs + ((size_t)(s * 2 + dir) * NB) * HH + (kc - 2) * 128);
        const int rs = (kc < 2) ? EMB : HH;
        #pragma unroll
        for (int r = 0; r < 2; ++r) {
          int i4 = tid + 512 * r;
          int bb = i4 >> 5;
          int kk = (i4 & 31) * 4;
          float4 v = *(const float4*)&src[bb * rs + kk];
          *(float4*)&us[bb * 132 + kk] = v;
        }
      }
      __syncthreads();
      const float* wr = (kc < 2) ? (Wih + (size_t)o * EMB + kc * 128)
                                 : (Whh + (size_t)o * HH + (kc - 2) * 128);
      #pragma unroll 8
      for (int q = 0; q < 32; ++q) {
        float4 uv = *(const float4*)&us[b * 132 + q * 4];
        float4 wv = *(const float4*)&wr[q * 4];
        acc = fmaf(uv.x, wv.x, acc);
        acc = fmaf(uv.y, wv.y, acc);
        acc = fmaf(uv.z, wv.z, acc);
        acc = fmaf(uv.w, wv.w, acc);
      }
    }
    glds[ol][b] = acc + bias2;
    __syncthreads();
    if (tid < 128) {
      float gi = glds[0 * 4 + uj][ub];
      float gf = glds[1 * 4 + uj][ub];
      float gg = glds[2 * 4 + uj][ub];
      float go = glds[3 * 4 + uj][ub];
      float c  = sigf(gf) * c_reg + sigf(gi) * tanhf(gg);
      c_reg = c;
      float h = sigf(go) * tanhf(c);
      int j = j0 + uj;
      stg1(&hs[((size_t)((s + 1) * 2 + dir) * NB + ub) * HH + j], h);
      if (dir == 0) {
        eo[((size_t)ub * TE + s) * CTXD + j] = (s < Lu) ? h : 0.0f;
      } else {
        int pos = (s < Lu) ? (Lu - 1 - s) : s;
        eo[((size_t)ub * TE + pos) * CTXD + HH + j] = (s < Lu) ? h : 0.0f;
      }
    }
    gbar(cnt, gen);
  }
}

// ---------------- Decoder: 256 blocks x 512 thr, persistent ----------------
__global__ void __launch_bounds__(512)
dec_kernel(const int* __restrict__ dec_in, const int* __restrict__ lens,
           const float* __restrict__ emb_tgt,
           const float* __restrict__ gWih, const float* __restrict__ gWhh,
           const float* __restrict__ gbih, const float* __restrict__ gbhh,
           const float* __restrict__ attn_W, const float* __restrict__ attn_b,
           const float* __restrict__ attn_v,
           float* __restrict__ ws)
{
  int* cnt = (int*)ws;
  int* gen = ((int*)ws) + 1;
  float* eo = ws + OEO;
  float* ep = ws + OEP;
  float* hd = ws + OHD;
  float* cx = ws + OCX;

  const int tid = threadIdx.x;
  const int bid = blockIdx.x;

  asm volatile("buffer_inv sc1" ::: "memory");

  // pre-phase: epre[b][t][a] = enc_out@attn_W[:1024] + attn_b ; hdec[0]=0
  {
    const int gt = bid * 512 + tid;
    if (gt < NB * TE * 8) {
      int a = gt & 7;
      int t = (gt >> 3) & 127;
      int b = gt >> 10;
      float acc = attn_b[a];
      const float* er = &eo[((size_t)b * TE + t) * CTXD];
      for (int d = 0; d < CTXD; d += 4) {
        float4 ev = *(const float4*)&er[d];
        acc = fmaf(ev.x, attn_W[(d + 0) * 8 + a], acc);
        acc = fmaf(ev.y, attn_W[(d + 1) * 8 + a], acc);
        acc = fmaf(ev.z, attn_W[(d + 2) * 8 + a], acc);
        acc = fmaf(ev.w, attn_W[(d + 3) * 8 + a], acc);
      }
      stg1(&ep[gt], acc);
    }
    if (gt < NB * HH) stg1(&hd[gt], 0.0f);
  }
  gbar(cnt, gen);

  __shared__ float hpp[64];
  __shared__ float hpv[8];
  __shared__ float elds[128];
  __shared__ float wlds[128];
  __shared__ float red[64];
  __shared__ float gi2[2][2][3][32];
  __shared__ float gh2[2][2][3][32];

  const int pb = bid >> 3;   // P2 batch
  const int ds = bid & 7;    // P2 ctx d-slice
  const int Lb = lens[pb];

  for (int s = 0; s < TD; ++s) {
    // ---- P2: attention scores, softmax, ctx ----
    {
      const float* hrow = &hd[(size_t)s * NB * HH + pb * HH];
      if (tid < 64) {
        int a = tid >> 3, p = tid & 7;
        float acc = 0.0f;
        const float* wp = &attn_W[(CTXD + p * 64) * 8 + a];
        const float* h8 = &hrow[p * 64];
        for (int q = 0; q < 64; ++q) acc = fmaf(h8[q], wp[q * 8], acc);
        hpp[tid] = acc;
      }
      __syncthreads();
      if (tid < 8) {
        float x = 0.0f;
        for (int p = 0; p < 8; ++p) x += hpp[tid * 8 + p];
        hpv[tid] = x;
      }
      __syncthreads();
      if (tid < 128) {
        float evv;
        if (tid < Lb) {
          evv = 0.0f;
          const float* e8 = &ep[((size_t)pb * TE + tid) * 8];
          #pragma unroll
          for (int a = 0; a < 8; ++a) evv += tanhf(e8[a] + hpv[a]) * attn_v[a];
        } else evv = -1e9f;
        elds[tid] = evv;
      }
      __syncthreads();
      if (tid < 64) red[tid] = fmaxf(elds[tid], elds[tid + 64]);
      __syncthreads();
      for (int w = 32; w > 0; w >>= 1) {
        if (tid < w) red[tid] = fmaxf(red[tid], red[tid + w]);
        __syncthreads();
      }
      float mx = red[0];
      __syncthreads();
      if (tid < 128) wlds[tid] = expf(elds[tid] - mx);
      __syncthreads();
      if (tid < 64) red[tid] = wlds[tid] + wlds[tid + 64];
      __syncthreads();
      for (int w = 32; w > 0; w >>= 1) {
        if (tid < w) red[tid] += red[tid + w];
        __syncthreads();
      }
      float inv = 1.0f / red[0];
      __syncthreads();
      if (tid < 128) {
        int d = ds * 128 + tid;
        float acc = 0.0f;
        const float* ebase = &eo[((size_t)pb * TE) * CTXD + d];
        for (int t = 0; t < TE; ++t)
          acc = fmaf(wlds[t], ebase[(size_t)t * CTXD], acc);
        stg1(&cx[((size_t)s * NB + pb) * CTXD + d], acc * inv);
      }
    }
    gbar(cnt, gen);
    // ---- P3: GRU cell -> hdec[s+1] ----
    {
      if (tid < 384) {
        int b  = tid & 31;
        int q  = tid >> 5;
        int g  = q % 3;
        int jl = (q / 3) & 1;
        int kh = q / 6;
        int j  = bid * 2 + jl;
        int row = g * HH + j;
        int tok = dec_in[b * TD + s];
        const float* wi  = &gWih[(size_t)row * (EMB + CTXD)];
        const float* wh  = &gWhh[(size_t)row * HH];
        const float* cxr = &cx[((size_t)s * NB + b) * CTXD];
        const float* hr  = &hd[(size_t)s * NB * HH + b * HH];
        float ai = 0.0f, ah = 0.0f;
        if (kh == 0) {
          const float* em = &emb_tgt[(size_t)tok * EMB];
          for (int k = 0; k < 256; k += 4) {
            float4 xv = *(const float4*)&em[k];
            float4 wv = *(const float4*)&wi[k];
            ai = fmaf(xv.x, wv.x, ai); ai = fmaf(xv.y, wv.y, ai);
            ai = fmaf(xv.z, wv.z, ai); ai = fmaf(xv.w, wv.w, ai);
          }
          for (int k = 256; k < 640; k += 4) {
            float4 xv = *(const float4*)&cxr[k - 256];
            float4 wv = *(const float4*)&wi[k];
            ai = fmaf(xv.x, wv.x, ai); ai = fmaf(xv.y, wv.y, ai);
            ai = fmaf(xv.z, wv.z, ai); ai = fmaf(xv.w, wv.w, ai);
          }
          for (int k = 0; k < 256; k += 4) {
            float4 hv = *(const float4*)&hr[k];
            float4 wv = *(const float4*)&wh[k];
            ah = fmaf(hv.x, wv.x, ah); ah = fmaf(hv.y, wv.y, ah);
            ah = fmaf(hv.z, wv.z, ah); ah = fmaf(hv.w, wv.w, ah);
          }
        } else {
          for (int k = 640; k < 1280; k += 4) {
            float4 xv = *(const float4*)&cxr[k - 256];
            float4 wv = *(const float4*)&wi[k];
            ai = fmaf(xv.x, wv.x, ai); ai = fmaf(xv.y, wv.y, ai);
            ai = fmaf(xv.z, wv.z, ai); ai = fmaf(xv.w, wv.w, ai);
          }
          for (int k = 256; k < 512; k += 4) {
            float4 hv = *(const float4*)&hr[k];
            float4 wv = *(const float4*)&wh[k];
            ah = fmaf(hv.x, wv.x, ah); ah = fmaf(hv.y, wv.y, ah);
            ah = fmaf(hv.z, wv.z, ah); ah = fmaf(hv.w, wv.w, ah);
          }
        }
        gi2[kh][jl][g][b] = ai;
        gh2[kh][jl][g][b] = ah;
      }
      __syncthreads();
      if (tid < 64) {
        int b = tid & 31, jl = tid >> 5;
        int j = bid * 2 + jl;
        float giR = gi2[0][jl][0][b] + gi2[1][jl][0][b] + gbih[j];
        float ghR = gh2[0][jl][0][b] + gh2[1][jl][0][b] + gbhh[j];
        float giZ = gi2[0][jl][1][b] + gi2[1][jl][1][b] + gbih[HH + j];
        float ghZ = gh2[0][jl][1][b] + gh2[1][jl][1][b] + gbhh[HH + j];
        float giN = gi2[0][jl][2][b] + gi2[1][jl][2][b] + gbih[2 * HH + j];
        float ghN = gh2[0][jl][2][b] + gh2[1][jl][2][b] + gbhh[2 * HH + j];
        float r = sigf(giR + ghR);
        float z = sigf(giZ + ghZ);
        float n = tanhf(giN + r * ghN);
        float hold = hd[(size_t)s * NB * HH + b * HH + j];
        float hnew = (1.0f - z) * n + z * hold;
        stg1(&hd[(size_t)(s + 1) * NB * HH + b * HH + j], hnew);
      }
    }
    gbar(cnt, gen);
  }
}

// ---------------- Classifier: [1024,512] @ clf_W^T [512,32000], relu ----------------
__global__ void __launch_bounds__(256)
clf_kernel(const float* __restrict__ hdec, const float* __restrict__ W,
           const float* __restrict__ bias, float* __restrict__ out)
{
  __shared__ __align__(16) float As[16][68];
  __shared__ __align__(16) float Bs[16][68];
  const int tid = threadIdx.x;
  const int tx = tid & 15, ty = tid >> 4;
  const int n0 = blockIdx.x * 64, m0 = blockIdx.y * 64;
  float acc[4][4] = {};
  const int lr = tid >> 2;
  const int lk = (tid & 3) * 4;
  const int r  = m0 + lr;                       // r = b*TD + t
  const float* arow = hdec + (((size_t)(r & 31) + 1) * NB + (r >> 5)) * HH;
  const float* brow = W + (size_t)(n0 + lr) * HH;

  for (int kc = 0; kc < HH; kc += 16) {
    float4 av = *(const float4*)&arow[kc + lk];
    float4 bv = *(const float4*)&brow[kc + lk];
    __syncthreads();
    As[lk + 0][lr] = av.x; As[lk + 1][lr] = av.y;
    As[lk + 2][lr] = av.z; As[lk + 3][lr] = av.w;
    Bs[lk + 0][lr] = bv.x; Bs[lk + 1][lr] = bv.y;
    Bs[lk + 2][lr] = bv.z; Bs[lk + 3][lr] = bv.w;
    __syncthreads();
    #pragma unroll
    for (int kk = 0; kk < 16; ++kk) {
      float4 a4 = *(const float4*)&As[kk][ty * 4];
      float4 b4 = *(const float4*)&Bs[kk][tx * 4];
      acc[0][0] = fmaf(a4.x, b4.x, acc[0][0]); acc[0][1] = fmaf(a4.x, b4.y, acc[0][1]);
      acc[0][2] = fmaf(a4.x, b4.z, acc[0][2]); acc[0][3] = fmaf(a4.x, b4.w, acc[0][3]);
      acc[1][0] = fmaf(a4.y, b4.x, acc[1][0]); acc[1][1] = fmaf(a4.y, b4.y, acc[1][1]);
      acc[1][2] = fmaf(a4.y, b4.z, acc[1][2]); acc[1][3] = fmaf(a4.y, b4.w, acc[1][3]);
      acc[2][0] = fmaf(a4.z, b4.x, acc[2][0]); acc[2][1] = fmaf(a4.z, b4.y, acc[2][1]);
      acc[2][2] = fmaf(a4.z, b4.z, acc[2][2]); acc[2][3] = fmaf(a4.z, b4.w, acc[2][3]);
      acc[3][0] = fmaf(a4.w, b4.x, acc[3][0]); acc[3][1] = fmaf(a4.w, b4.y, acc[3][1]);
      acc[3][2] = fmaf(a4.w, b4.z, acc[3][2]); acc[3][3] = fmaf(a4.w, b4.w, acc[3][3]);
    }
  }
  const int col = n0 + tx * 4;
  float4 bb4 = *(const float4*)&bias[col];
  #pragma unroll
  for (int i = 0; i < 4; ++i) {
    int row = m0 + ty * 4 + i;
    float4 o;
    o.x = fmaxf(acc[i][0] + bb4.x, 0.0f);
    o.y = fmaxf(acc[i][1] + bb4.y, 0.0f);
    o.z = fmaxf(acc[i][2] + bb4.z, 0.0f);
    o.w = fmaxf(acc[i][3] + bb4.w, 0.0f);
    *(float4*)&out[(size_t)row * VOC + col] = o;
  }
}

extern "C" void kernel_launch(void* const* d_in, const int* in_sizes, int n_in,
                              void* d_out, int out_size, void* d_ws, size_t ws_size,
                              hipStream_t stream)
{
  if (ws_size < (size_t)WSEND * 4) return;  // visible-failure guard

  const int* enc_in  = (const int*)d_in[0];
  const int* enc_len = (const int*)d_in[1];
  const int* dec_in  = (const int*)d_in[2];
  const float* emb_src = (const float*)d_in[4];
  const float* emb_tgt = (const float*)d_in[5];
  const float* Wih_f = (const float*)d_in[6];
  const float* Whh_f = (const float*)d_in[7];
  const float* bih_f = (const float*)d_in[8];
  const float* bhh_f = (const float*)d_in[9];
  const float* Wih_b = (const float*)d_in[10];
  const float* Whh_b = (const float*)d_in[11];
  const float* bih_b = (const float*)d_in[12];
  const float* bhh_b = (const float*)d_in[13];
  const float* gWih  = (const float*)d_in[14];
  const float* gWhh  = (const float*)d_in[15];
  const float* gbih  = (const float*)d_in[16];
  const float* gbhh  = (const float*)d_in[17];
  const float* attn_W = (const float*)d_in[18];
  const float* attn_b = (const float*)d_in[19];
  const float* attn_v = (const float*)d_in[20];
  const float* clf_W = (const float*)d_in[21];
  const float* clf_b = (const float*)d_in[22];
  float* ws  = (float*)d_ws;
  float* out = (float*)d_out;

  hipMemsetAsync(d_ws, 0, 256, stream);  // barrier state
  scan_kernel<<<256, 512, 0, stream>>>(enc_in, enc_len, emb_src,
      Wih_f, Whh_f, bih_f, bhh_f, Wih_b, Whh_b, bih_b, bhh_b, ws);
  dec_kernel<<<256, 512, 0, stream>>>(dec_in, enc_len, emb_tgt,
      gWih, gWhh, gbih, gbhh, attn_W, attn_b, attn_v, ws);
  dim3 cg(VOC / 64, (NB * TD) / 64);
  clf_kernel<<<cg, 256, 0, stream>>>(ws + OHD, clf_W, clf_b, out);
}